// Round 1
// baseline (1920.187 us; speedup 1.0000x reference)
//
#include <hip/hip_runtime.h>

// ---------------------------------------------------------------------------
// EnhancedGraphEncoder: 4-layer GCN + BN + ReLU + skip + global mean pool
// N=100000 nodes, E=1.6M edges (+self loops), dims 128->128->128->128->64,
// 128 graphs. All f32.
// ---------------------------------------------------------------------------

__device__ __forceinline__ float4 f4fma(float a, float4 b, float4 c) {
    c.x = fmaf(a, b.x, c.x);
    c.y = fmaf(a, b.y, c.y);
    c.z = fmaf(a, b.z, c.z);
    c.w = fmaf(a, b.w, c.w);
    return c;
}

// ------------------------- preprocessing kernels ---------------------------

__global__ void k_deg(const int* __restrict__ edst, int E, int* __restrict__ deg) {
    int e = blockIdx.x * blockDim.x + threadIdx.x;
    if (e < E) atomicAdd(&deg[edst[e]], 1);
}

__global__ void k_dinv(const int* __restrict__ deg, int n, float* __restrict__ dinv) {
    int i = blockIdx.x * blockDim.x + threadIdx.x;
    if (i < n) {
        int c = deg[i] + 1;  // + self loop
        dinv[i] = rsqrtf((float)c);
    }
}

// scan phase A: per-block (1024 elems) sums of (deg[i]+1)
__global__ void k_bsum(const int* __restrict__ deg, int n, int* __restrict__ bsum) {
    __shared__ int sd[256];
    int base = blockIdx.x * 1024;
    int end = base + 1024; if (end > n) end = n;
    int s = 0;
    for (int i = base + threadIdx.x; i < end; i += 256) s += deg[i] + 1;
    sd[threadIdx.x] = s;
    __syncthreads();
    for (int off = 128; off > 0; off >>= 1) {
        if (threadIdx.x < off) sd[threadIdx.x] += sd[threadIdx.x + off];
        __syncthreads();
    }
    if (threadIdx.x == 0) bsum[blockIdx.x] = sd[0];
}

// scan phase B: serial exclusive scan of block sums (B ~ 98, trivial)
__global__ void k_scanb(int* __restrict__ bsum, int B) {
    int run = 0;
    for (int i = 0; i < B; ++i) { int v = bsum[i]; bsum[i] = run; run += v; }
}

// scan phase C: local scan + block offset -> exclusive offsets
__global__ void k_offs(const int* __restrict__ deg, int n, const int* __restrict__ bsum,
                       int* __restrict__ offs) {
    __shared__ int sd[256];
    int base = blockIdx.x * 1024;
    int carry = bsum[blockIdx.x];
    for (int tile = 0; tile < 4; ++tile) {
        int i = base + tile * 256 + threadIdx.x;
        int v = (i < n) ? (deg[i] + 1) : 0;
        sd[threadIdx.x] = v;
        __syncthreads();
        int x = v;
        for (int off = 1; off < 256; off <<= 1) {
            int y = (threadIdx.x >= off) ? sd[threadIdx.x - off] : 0;
            __syncthreads();
            x += y;
            sd[threadIdx.x] = x;
            __syncthreads();
        }
        if (i < n) offs[i] = carry + x - v;        // exclusive
        if (i == n - 1) offs[n] = carry + x;       // total
        carry += sd[255];
        __syncthreads();
    }
}

__global__ void k_fill_edges(const int* __restrict__ esrc, const int* __restrict__ edst, int E,
                             const float* __restrict__ dinv, const int* __restrict__ offs,
                             int* __restrict__ cursor, int* __restrict__ csrs,
                             float* __restrict__ csrn) {
    int e = blockIdx.x * blockDim.x + threadIdx.x;
    if (e < E) {
        int s = esrc[e], d = edst[e];
        int slot = offs[d] + atomicAdd(&cursor[d], 1);
        csrs[slot] = s;
        csrn[slot] = dinv[s] * dinv[d];
    }
}

__global__ void k_fill_self(int n, const float* __restrict__ dinv, const int* __restrict__ offs,
                            int* __restrict__ cursor, int* __restrict__ csrs,
                            float* __restrict__ csrn) {
    int i = blockIdx.x * blockDim.x + threadIdx.x;
    if (i < n) {
        int slot = offs[i] + atomicAdd(&cursor[i], 1);
        csrs[slot] = i;
        csrn[slot] = dinv[i] * dinv[i];
    }
}

__global__ void k_gcnt(const int* __restrict__ batch, int n, int* __restrict__ gcnt) {
    int i = blockIdx.x * blockDim.x + threadIdx.x;
    if (i < n) atomicAdd(&gcnt[batch[i]], 1);
}

// ------------------------------- GEMM --------------------------------------
// O[n,FOUT] = H[n,128] @ W[128,FOUT].  W staged in LDS, 128-row tiles staged
// in LDS, each thread computes R rows x 4 consecutive outputs in registers.

template <int FOUT, int R>
__global__ __launch_bounds__(512) void k_gemm(const float* __restrict__ H,
                                              const float* __restrict__ Wg,
                                              float* __restrict__ O, int n) {
    constexpr int TPR = FOUT / 4;        // threads per row-group
    constexpr int GROUPS = 512 / TPR;    // row-groups per block
    constexpr int ROWS = GROUPS * R;     // rows per block (128)
    __shared__ float Wl[128 * FOUT];
    __shared__ float rb[ROWS * 128];

    for (int i = threadIdx.x * 4; i < 128 * FOUT; i += 512 * 4)
        *(float4*)&Wl[i] = *(const float4*)&Wg[i];

    const int row0 = blockIdx.x * ROWS;
    for (int i = threadIdx.x * 4; i < ROWS * 128; i += 512 * 4) {
        int r = i >> 7;
        float4 v = make_float4(0.f, 0.f, 0.f, 0.f);
        if (row0 + r < n) v = *(const float4*)&H[row0 * 128 + i];
        *(float4*)&rb[i] = v;
    }
    __syncthreads();

    const int g = threadIdx.x / TPR;
    const int o4 = (threadIdx.x % TPR) * 4;
    float4 acc[R];
#pragma unroll
    for (int r = 0; r < R; ++r) acc[r] = make_float4(0.f, 0.f, 0.f, 0.f);

    const float* wp = Wl + o4;
    const float* rp = rb + g * R * 128;
#pragma unroll 2
    for (int k = 0; k < 128; k += 4) {
        float4 w0 = *(const float4*)&wp[(k + 0) * FOUT];
        float4 w1 = *(const float4*)&wp[(k + 1) * FOUT];
        float4 w2 = *(const float4*)&wp[(k + 2) * FOUT];
        float4 w3 = *(const float4*)&wp[(k + 3) * FOUT];
#pragma unroll
        for (int r = 0; r < R; ++r) {
            float4 h4 = *(const float4*)&rp[r * 128 + k];
            acc[r] = f4fma(h4.x, w0, acc[r]);
            acc[r] = f4fma(h4.y, w1, acc[r]);
            acc[r] = f4fma(h4.z, w2, acc[r]);
            acc[r] = f4fma(h4.w, w3, acc[r]);
        }
    }
#pragma unroll
    for (int r = 0; r < R; ++r) {
        int row = row0 + g * R + r;
        if (row < n) *(float4*)&O[row * FOUT + o4] = acc[r];
    }
}

// ---------------------------- aggregation ----------------------------------
// agg[d,f] = sum_{e: dst=d} hW[src_e, f] * norm_e   (CSR by dst)
// fused: per-feature sum & sumsq for BatchNorm (block reduce + atomics)

template <int F>
__global__ __launch_bounds__(256) void k_agg(const float* __restrict__ hW,
                                             const int* __restrict__ csrs,
                                             const float* __restrict__ csrn,
                                             const int* __restrict__ offs,
                                             float* __restrict__ agg,
                                             float* __restrict__ stats, int n) {
    constexpr int NPB = 256 / F;
    const int f = threadIdx.x % F;
    const int sub = threadIdx.x / F;
    float lsum = 0.f, lsq = 0.f;

    for (int node = blockIdx.x * NPB + sub; node < n; node += gridDim.x * NPB) {
        const int beg = offs[node];
        const int end = offs[node + 1];
        float acc = 0.f;
        for (int j = beg; j < end; ++j) {
            const int s = csrs[j];
            const float w = csrn[j];
            acc = fmaf(hW[s * F + f], w, acc);
        }
        agg[node * F + f] = acc;
        lsum += acc;
        lsq = fmaf(acc, acc, lsq);
    }

    __shared__ float sd[512];
    sd[threadIdx.x] = lsum;
    sd[256 + threadIdx.x] = lsq;
    __syncthreads();
    if (threadIdx.x < F) {
        float s1 = sd[threadIdx.x], s2 = sd[256 + threadIdx.x];
#pragma unroll
        for (int c = F; c < 256; c += F) {
            s1 += sd[threadIdx.x + c];
            s2 += sd[256 + threadIdx.x + c];
        }
        atomicAdd(&stats[f], s1);
        atomicAdd(&stats[F + f], s2);
    }
}

// -------------------------- BN coef + apply --------------------------------

__global__ void k_coef(const float* __restrict__ stats, const float* __restrict__ g,
                       const float* __restrict__ be, float* __restrict__ coef, int F,
                       float inv_n) {
    int f = threadIdx.x;
    if (f < F) {
        float mean = stats[f] * inv_n;
        float var = stats[F + f] * inv_n - mean * mean;
        var = fmaxf(var, 0.f);
        float sc = g[f] * rsqrtf(var + 1e-5f);
        coef[f] = sc;
        coef[F + f] = be[f] - mean * sc;
    }
}

// out = [relu](scale*in + shift) [+ sw*prev]   (F = 128, vectorized float4)
template <bool RELU, bool SKIP>
__global__ __launch_bounds__(256) void k_bnapply(const float* __restrict__ in,
                                                 const float* __restrict__ prev,
                                                 const float* __restrict__ swp,
                                                 const float* __restrict__ coef,
                                                 float* __restrict__ out, int n4) {
    float sw = 0.f;
    if constexpr (SKIP) sw = *swp;
    for (int i = blockIdx.x * blockDim.x + threadIdx.x; i < n4;
         i += gridDim.x * blockDim.x) {
        int f4 = (i & 31) << 2;
        const float4 sc = *(const float4*)&coef[f4];
        const float4 sh = *(const float4*)&coef[128 + f4];
        float4 v = ((const float4*)in)[i];
        float4 r;
        r.x = fmaf(v.x, sc.x, sh.x);
        r.y = fmaf(v.y, sc.y, sh.y);
        r.z = fmaf(v.z, sc.z, sh.z);
        r.w = fmaf(v.w, sc.w, sh.w);
        if constexpr (RELU) {
            r.x = fmaxf(r.x, 0.f); r.y = fmaxf(r.y, 0.f);
            r.z = fmaxf(r.z, 0.f); r.w = fmaxf(r.w, 0.f);
        }
        if constexpr (SKIP) {
            float4 pv = ((const float4*)prev)[i];
            r.x = fmaf(sw, pv.x, r.x);
            r.y = fmaf(sw, pv.y, r.y);
            r.z = fmaf(sw, pv.z, r.z);
            r.w = fmaf(sw, pv.w, r.w);
        }
        ((float4*)out)[i] = r;
    }
}

// ----------------------- layer-3 BN + mean pool -----------------------------
// out[g,f] += sum over nodes of (scale*agg+shift); LDS-accumulated per block.

__global__ __launch_bounds__(256) void k_bnpool(const float* __restrict__ C,
                                                const int* __restrict__ batch,
                                                const float* __restrict__ coef,
                                                float* __restrict__ out, int n) {
    __shared__ float pool[128 * 64];
    for (int i = threadIdx.x; i < 128 * 64; i += 256) pool[i] = 0.f;
    __syncthreads();
    const int f = threadIdx.x & 63;
    const int sub = threadIdx.x >> 6;  // 0..3
    const float sc = coef[f];
    const float sh = coef[64 + f];
    for (int node = blockIdx.x * 4 + sub; node < n; node += gridDim.x * 4) {
        float v = fmaf(sc, C[node * 64 + f], sh);
        int g = batch[node];
        atomicAdd(&pool[g * 64 + f], v);
    }
    __syncthreads();
    for (int i = threadIdx.x; i < 128 * 64; i += 256) atomicAdd(&out[i], pool[i]);
}

__global__ void k_div(float* __restrict__ out, const int* __restrict__ gcnt, int total) {
    int i = blockIdx.x * blockDim.x + threadIdx.x;
    if (i < total) {
        int g = i >> 6;
        int c = gcnt[g];
        if (c < 1) c = 1;
        out[i] = out[i] / (float)c;
    }
}

// ------------------------------ launcher ------------------------------------

static inline size_t align256(size_t x) { return (x + 255) & ~(size_t)255; }

extern "C" void kernel_launch(void* const* d_in, const int* in_sizes, int n_in,
                              void* d_out, int out_size, void* d_ws, size_t ws_size,
                              hipStream_t stream) {
    const float* x    = (const float*)d_in[0];
    const int* ei     = (const int*)d_in[1];
    const int* batch  = (const int*)d_in[2];
    const float* W0   = (const float*)d_in[3];
    const float* g0   = (const float*)d_in[5];
    const float* be0  = (const float*)d_in[6];
    const float* W1   = (const float*)d_in[7];
    const float* g1   = (const float*)d_in[9];
    const float* be1  = (const float*)d_in[10];
    const float* W2   = (const float*)d_in[11];
    const float* g2   = (const float*)d_in[13];
    const float* be2  = (const float*)d_in[14];
    const float* W3   = (const float*)d_in[15];
    const float* g3   = (const float*)d_in[17];
    const float* be3  = (const float*)d_in[18];
    const float* swp  = (const float*)d_in[19];

    const int N = in_sizes[0] / 128;
    const int E = in_sizes[1] / 2;
    const int T = E + N;
    const int* esrc = ei;
    const int* edst = ei + E;

    char* p = (char*)d_ws;
    auto carve = [&](size_t bytes) -> char* {
        char* r = p;
        p += align256(bytes);
        return r;
    };
    int*   deg    = (int*)carve((size_t)N * 4);
    float* dinv   = (float*)carve((size_t)N * 4);
    int*   offs   = (int*)carve((size_t)(N + 1) * 4);
    int*   cursor = (int*)carve((size_t)N * 4);
    int*   bsum   = (int*)carve(256 * 4);
    int*   csrs   = (int*)carve((size_t)T * 4);
    float* csrn   = (float*)carve((size_t)T * 4);
    float* stats  = (float*)carve(4 * 256 * 4);
    float* coef   = (float*)carve(4 * 256 * 4);
    int*   gcnt   = (int*)carve(128 * 4);
    float* bufA   = (float*)carve((size_t)N * 128 * 4);
    float* bufB   = (float*)carve((size_t)N * 128 * 4);
    float* bufC   = (float*)carve((size_t)N * 128 * 4);

    hipMemsetAsync(deg, 0, (size_t)N * 4, stream);
    hipMemsetAsync(cursor, 0, (size_t)N * 4, stream);
    hipMemsetAsync(stats, 0, 4 * 256 * 4, stream);
    hipMemsetAsync(gcnt, 0, 128 * 4, stream);
    hipMemsetAsync(d_out, 0, (size_t)out_size * 4, stream);

    // graph preprocessing: degrees, norms, CSR by dst
    k_deg<<<(E + 255) / 256, 256, 0, stream>>>(edst, E, deg);
    k_dinv<<<(N + 255) / 256, 256, 0, stream>>>(deg, N, dinv);
    const int B = (N + 1023) / 1024;
    k_bsum<<<B, 256, 0, stream>>>(deg, N, bsum);
    k_scanb<<<1, 1, 0, stream>>>(bsum, B);
    k_offs<<<B, 256, 0, stream>>>(deg, N, bsum, offs);
    k_fill_edges<<<(E + 255) / 256, 256, 0, stream>>>(esrc, edst, E, dinv, offs, cursor,
                                                      csrs, csrn);
    k_fill_self<<<(N + 255) / 256, 256, 0, stream>>>(N, dinv, offs, cursor, csrs, csrn);
    k_gcnt<<<(N + 255) / 256, 256, 0, stream>>>(batch, N, gcnt);

    const float inv_n = 1.0f / (float)N;
    const int gemm_grid = (N + 127) / 128;

    // layer 0: x @ W0 -> agg -> BN+ReLU -> bufA
    k_gemm<128, 8><<<gemm_grid, 512, 0, stream>>>(x, W0, bufB, N);
    k_agg<128><<<2048, 256, 0, stream>>>(bufB, csrs, csrn, offs, bufC, stats + 0, N);
    k_coef<<<1, 128, 0, stream>>>(stats + 0, g0, be0, coef + 0, 128, inv_n);
    k_bnapply<true, false><<<2048, 256, 0, stream>>>(bufC, nullptr, nullptr, coef + 0,
                                                     bufA, N * 32);
    // layer 1: bufA @ W1 -> agg -> BN+ReLU + 0.1*bufA -> bufB
    k_gemm<128, 8><<<gemm_grid, 512, 0, stream>>>(bufA, W1, bufB, N);
    k_agg<128><<<2048, 256, 0, stream>>>(bufB, csrs, csrn, offs, bufC, stats + 256, N);
    k_coef<<<1, 128, 0, stream>>>(stats + 256, g1, be1, coef + 256, 128, inv_n);
    k_bnapply<true, true><<<2048, 256, 0, stream>>>(bufC, bufA, swp, coef + 256, bufB,
                                                    N * 32);
    // layer 2: bufB @ W2 -> agg -> BN+ReLU + 0.1*bufB -> bufA
    k_gemm<128, 8><<<gemm_grid, 512, 0, stream>>>(bufB, W2, bufA, N);
    k_agg<128><<<2048, 256, 0, stream>>>(bufA, csrs, csrn, offs, bufC, stats + 512, N);
    k_coef<<<1, 128, 0, stream>>>(stats + 512, g2, be2, coef + 512, 128, inv_n);
    k_bnapply<true, true><<<2048, 256, 0, stream>>>(bufC, bufB, swp, coef + 512, bufA,
                                                    N * 32);
    // layer 3: bufA @ W3 (128->64) -> agg -> BN (no relu) -> mean pool
    k_gemm<64, 4><<<gemm_grid, 512, 0, stream>>>(bufA, W3, bufB, N);
    k_agg<64><<<2048, 256, 0, stream>>>(bufB, csrs, csrn, offs, bufC, stats + 768, N);
    k_coef<<<1, 64, 0, stream>>>(stats + 768, g3, be3, coef + 768, 64, inv_n);
    k_bnpool<<<128, 256, 0, stream>>>(bufC, batch, coef + 768, (float*)d_out, N);
    k_div<<<(out_size + 255) / 256, 256, 0, stream>>>((float*)d_out, gcnt, out_size);
}